// Round 4
// baseline (1003.618 us; speedup 1.0000x reference)
//
#include <hip/hip_runtime.h>
#include <cstdint>
#include <cstddef>

#define D_   384
#define Hn   6
#define HDm  64
#define T_   256
#define B_   128
#define NROW (B_ * T_)   // 32768

typedef __bf16  bf16x8 __attribute__((ext_vector_type(8)));
typedef float   f32x4  __attribute__((ext_vector_type(4)));
typedef const __attribute__((address_space(1))) void gvoid;
typedef __attribute__((address_space(3))) void lvoid;

// ---------- helpers ----------
__device__ inline uint32_t bf16rn(float f) {
  uint32_t u = __float_as_uint(f);
  return (u + 0x7FFFu + ((u >> 16) & 1u)) >> 16;
}

// ---------- LayerNorm: fp32 in -> bf16 out, one 128-thread block per row ----------
__global__ __launch_bounds__(128) void ln_kernel(const float* __restrict__ x,
                                                 const float* __restrict__ g,
                                                 const float* __restrict__ b,
                                                 uint16_t* __restrict__ out) {
  int row = blockIdx.x, tid = threadIdx.x;
  const float* xr = x + (size_t)row * D_;
  float v0 = xr[tid], v1 = xr[tid + 128], v2 = xr[tid + 256];
  float s  = v0 + v1 + v2;
  float ss = v0 * v0 + v1 * v1 + v2 * v2;
#pragma unroll
  for (int off = 32; off > 0; off >>= 1) {
    s  += __shfl_down(s, off);
    ss += __shfl_down(ss, off);
  }
  __shared__ float red[4];
  if ((tid & 63) == 0) { red[(tid >> 6) * 2] = s; red[(tid >> 6) * 2 + 1] = ss; }
  __syncthreads();
  float S = red[0] + red[2], SS = red[1] + red[3];
  float mu  = S * (1.0f / D_);
  float var = SS * (1.0f / D_) - mu * mu;
  float inv = rsqrtf(var + 1e-5f);
  uint16_t* orow = out + (size_t)row * D_;
  orow[tid]       = (uint16_t)bf16rn((v0 - mu) * inv * g[tid]       + b[tid]);
  orow[tid + 128] = (uint16_t)bf16rn((v1 - mu) * inv * g[tid + 128] + b[tid + 128]);
  orow[tid + 256] = (uint16_t)bf16rn((v2 - mu) * inv * g[tid + 256] + b[tid + 256]);
}

// ---------- pack Wq/Wk/Wv [H,D,HD] -> bf16 Wt[col=1152][d=384] (K-contiguous) ----------
__global__ __launch_bounds__(256) void pack_qkv_w(const float* __restrict__ Wq,
                                                  const float* __restrict__ Wk,
                                                  const float* __restrict__ Wv,
                                                  uint16_t* __restrict__ Wo) {
  int idx = blockIdx.x * 256 + threadIdx.x;      // 1152*384 total
  if (idx >= 1152 * D_) return;
  int col = idx / D_, d = idx % D_;
  int which = col / 384, c2 = col % 384;
  int h = c2 / HDm, k = c2 % HDm;
  const float* W = (which == 0) ? Wq : (which == 1) ? Wk : Wv;
  Wo[idx] = (uint16_t)bf16rn(W[((size_t)h * D_ + d) * HDm + k]);
}

// ---------- transpose-pack W[K,N] -> bf16 Wt[N,K] ----------
__global__ __launch_bounds__(256) void pack_wt(const float* __restrict__ W,
                                               uint16_t* __restrict__ Wt,
                                               int K, int N) {
  int idx = blockIdx.x * 256 + threadIdx.x;
  if (idx >= K * N) return;
  int n = idx / K, k = idx % K;
  Wt[idx] = (uint16_t)bf16rn(W[(size_t)k * N + n]);
}

// ---------- persistent-B barrier-free GEMM: C[M,N] = A[M,K] @ Bt[N,K]^T ----------
// BM=256, BN=128, 4 waves; wave w owns rows [w*64, w*64+64) x ALL 128 cols.
// B-slice [128 cols x 384 K] staged ONCE per K-tile into 96 KB LDS, chunk-major
// layout Bs[kchunk c][col]: a 16-lane frag read = 256 B contiguous (2 lanes/bank,
// conflict-free, no swizzle). A is NEVER in LDS: each wave streams its own rows
// global->reg (wave-private => no sharing => no barriers). The 12-chunk K-tile
// loop is fully unrolled, ZERO barriers inside: no vmcnt(0) drain, no lockstep;
// A/B load latency hides under the unrolled MFMA stream (ds:MFMA = 1:4).
// Per K-chunk per wave: 4 global A-loads + 8 ds_read_b128 + 32 MFMA.
// Sync cost: 2 __syncthreads per K-tile (K=384: 2 total; K=1536: 8 total).
// Requires K%384==0, M%256==0, N%128==0 (all four shapes comply).
__global__ __launch_bounds__(256, 1) void gemm_pb(const uint16_t* __restrict__ A,
                                                  const uint16_t* __restrict__ Bt,
                                                  const float* __restrict__ bias,
                                                  const float* __restrict__ resid,
                                                  void* __restrict__ Cout,
                                                  int M, int N, int K,
                                                  int relu, int store_f32) {
  __shared__ uint16_t Bs[48 * 1024];     // [c=0..47][col=0..127] 16B cells, 96 KB
  int tid = threadIdx.x;
  int bm = blockIdx.x * 256, bn = blockIdx.y * 128;
  int lane = tid & 63, wave = tid >> 6;
  int wm = wave << 6;                 // wave rows: 64 each
  int lr = lane & 15;                 // row-within-16
  int q  = lane >> 4;                 // k-chunk selector (0..3)
  int r0 = q << 2;                    // C row base within 16

  // per-wave A row pointers (wave-private, global)
  const uint16_t* pa[4];
#pragma unroll
  for (int i = 0; i < 4; ++i)
    pa[i] = A + (size_t)(bm + wm + i * 16 + lr) * K + q * 8;

  // B frag LDS base (elements): cell (c, col) at element c*1024 + col*8
  int bbase = q * 1024 + lr * 8;      // + ks*4096 + j*128 at use site

  f32x4 acc[4][8];
  const f32x4 zero = {0.f, 0.f, 0.f, 0.f};
#pragma unroll
  for (int i = 0; i < 4; ++i)
#pragma unroll
    for (int j = 0; j < 8; ++j) acc[i][j] = zero;

  int nkt = K / 384;                  // 1 (K=384) or 4 (K=1536)
  for (int kt = 0; kt < nkt; ++kt) {
    // ---- stage B K-tile: 96 regions of 1 KB, region m = s*4 + wave ----
    if (kt) __syncthreads();          // all reads of Bs from previous tile done
#pragma unroll
    for (int s = 0; s < 24; ++s) {
      int m = s * 4 + wave;
      int c = m >> 1;                 // k-chunk 0..47
      int col = ((m & 1) << 6) + lane;
      const uint16_t* gp = Bt + (size_t)(bn + col) * K + kt * 384 + c * 8;
      __builtin_amdgcn_global_load_lds((gvoid*)gp, (lvoid*)((char*)Bs + m * 1024), 16, 0, 0);
    }
    asm volatile("s_waitcnt vmcnt(0)" ::: "memory");
    __syncthreads();                  // Bs tile visible block-wide

    // ---- barrier-free K loop: 12 chunks, fully unrolled ----
    const uint16_t* pA0 = pa[0] + kt * 384;
    const uint16_t* pA1 = pa[1] + kt * 384;
    const uint16_t* pA2 = pa[2] + kt * 384;
    const uint16_t* pA3 = pa[3] + kt * 384;
#pragma unroll
    for (int ks = 0; ks < 12; ++ks) {
      bf16x8 af[4], bfr[8];
      af[0] = *(const bf16x8*)(pA0 + ks * 32);
      af[1] = *(const bf16x8*)(pA1 + ks * 32);
      af[2] = *(const bf16x8*)(pA2 + ks * 32);
      af[3] = *(const bf16x8*)(pA3 + ks * 32);
#pragma unroll
      for (int j = 0; j < 8; ++j)
        bfr[j] = *(const bf16x8*)&Bs[bbase + ks * 4096 + j * 128];
#pragma unroll
      for (int i = 0; i < 4; ++i)
#pragma unroll
        for (int j = 0; j < 8; ++j)
          acc[i][j] = __builtin_amdgcn_mfma_f32_16x16x32_bf16(af[i], bfr[j], acc[i][j], 0, 0, 0);
    }
  }

#pragma unroll
  for (int i = 0; i < 4; ++i) {
#pragma unroll
    for (int r = 0; r < 4; ++r) {
      int rr = bm + wm + i * 16 + r0 + r;
#pragma unroll
      for (int j = 0; j < 8; ++j) {
        int col = bn + j * 16 + lr;
        float v = acc[i][j][r];
        if (bias)  v += bias[col];
        if (relu)  v = fmaxf(v, 0.0f);
        if (resid) v += resid[(size_t)rr * N + col];
        if (store_f32) ((float*)Cout)[(size_t)rr * N + col] = v;
        else           ((uint16_t*)Cout)[(size_t)rr * N + col] = (uint16_t)bf16rn(v);
      }
    }
  }
}

// ---------- MFMA flash attention: one block per (b,h), 4 waves, wave w = rows w*64..w*64+63 ----------
// qkv (bf16) row (b*T+t): cols [0,384)=q(h*64+d), [384,768)=k, [768,1152)=v
__global__ __launch_bounds__(256, 2) void attn_mfma(const uint16_t* __restrict__ qkv,
                                                    uint16_t* __restrict__ o) {
  __shared__ uint16_t Kt[64 * 72];        // K-tile [s][d], pad 72 (9216 B)
  __shared__ uint16_t Vt[64 * 72];        // V-tile transposed [d][s], pad 72 (9216 B)
  __shared__ uint16_t Pb[4 * 64 * 72];    // per-wave P staging (36864 B)
  int bh = blockIdx.x;
  int b = bh / Hn, h = bh % Hn;
  int tid = threadIdx.x;
  int lane = tid & 63, w = tid >> 6;
  int ln = lane & 15, q = lane >> 4;
  int kq = q * 8;
  int m0 = w * 64;
  const uint16_t* base = qkv + (size_t)b * T_ * 1152;

  bf16x8 af[4][2];
#pragma unroll
  for (int i = 0; i < 4; ++i)
#pragma unroll
    for (int ks = 0; ks < 2; ++ks)
      af[i][ks] = *(const bf16x8*)(base + (size_t)(m0 + i * 16 + ln) * 1152 + h * HDm + ks * 32 + kq);

  f32x4 o_[4][4], m_[4], l_[4];
  const f32x4 zero = {0.f, 0.f, 0.f, 0.f};
#pragma unroll
  for (int i = 0; i < 4; ++i) {
    m_[i] = {-1e30f, -1e30f, -1e30f, -1e30f};
    l_[i] = zero;
#pragma unroll
    for (int n = 0; n < 4; ++n) o_[i][n] = zero;
  }
  const float cs = 0.07362222f;  // (1/sqrt(384)) * log2(e)

  for (int jt = 0; jt < 4; ++jt) {
    if (jt) __syncthreads();
#pragma unroll
    for (int t = 0; t < 2; ++t) {
      int c = t * 256 + tid;
      int s = c >> 3, d0 = (c & 7) << 3;
      *(uint4*)&Kt[s * 72 + d0] =
          *(const uint4*)(base + (size_t)(jt * 64 + s) * 1152 + 384 + h * HDm + d0);
    }
    {
      int sv = tid & 63, dv = (tid >> 6) << 4;
      const uint16_t* gv = base + (size_t)(jt * 64 + sv) * 1152 + 768 + h * HDm + dv;
      uint16_t tmp[16];
      *(uint4*)&tmp[0] = *(const uint4*)gv;
      *(uint4*)&tmp[8] = *(const uint4*)(gv + 8);
#pragma unroll
      for (int jj = 0; jj < 16; ++jj) Vt[(dv + jj) * 72 + sv] = tmp[jj];
    }
    __syncthreads();

    if (w >= jt) {
      f32x4 s2[4][4];
#pragma unroll
      for (int i = 0; i < 4; ++i)
#pragma unroll
        for (int j = 0; j < 4; ++j) s2[i][j] = zero;
#pragma unroll
      for (int ks = 0; ks < 2; ++ks) {
        bf16x8 bf[4];
#pragma unroll
        for (int j = 0; j < 4; ++j)
          bf[j] = *(const bf16x8*)&Kt[(j * 16 + ln) * 72 + ks * 32 + kq];
#pragma unroll
        for (int i = 0; i < 4; ++i)
#pragma unroll
          for (int j = 0; j < 4; ++j)
            s2[i][j] = __builtin_amdgcn_mfma_f32_16x16x32_bf16(af[i][ks], bf[j], s2[i][j], 0, 0, 0);
      }
#pragma unroll
      for (int i = 0; i < 4; ++i) {
#pragma unroll
        for (int j = 0; j < 4; ++j)
#pragma unroll
          for (int r = 0; r < 4; ++r) s2[i][j][r] *= cs;
        if (jt == w) {
#pragma unroll
          for (int j = 0; j < 4; ++j)
#pragma unroll
            for (int r = 0; r < 4; ++r)
              if (j * 16 + ln > i * 16 + q * 4 + r) s2[i][j][r] = -1e30f;
        }
        f32x4 rm;
#pragma unroll
        for (int r = 0; r < 4; ++r)
          rm[r] = fmaxf(fmaxf(s2[i][0][r], s2[i][1][r]), fmaxf(s2[i][2][r], s2[i][3][r]));
#pragma unroll
        for (int off = 1; off < 16; off <<= 1)
#pragma unroll
          for (int r = 0; r < 4; ++r)
            rm[r] = fmaxf(rm[r], __shfl_xor(rm[r], off));
        f32x4 mn, al, ps;
#pragma unroll
        for (int r = 0; r < 4; ++r) {
          mn[r] = fmaxf(m_[i][r], rm[r]);
          al[r] = exp2f(m_[i][r] - mn[r]);
          ps[r] = 0.f;
        }
        m_[i] = mn;
#pragma unroll
        for (int j = 0; j < 4; ++j)
#pragma unroll
          for (int r = 0; r < 4; ++r) {
            float p = exp2f(s2[i][j][r] - mn[r]);
            s2[i][j][r] = p;
            ps[r] += p;
          }
#pragma unroll
        for (int r = 0; r < 4; ++r) l_[i][r] = l_[i][r] * al[r] + ps[r];
#pragma unroll
        for (int n = 0; n < 4; ++n)
#pragma unroll
          for (int r = 0; r < 4; ++r) o_[i][n][r] *= al[r];
#pragma unroll
        for (int j = 0; j < 4; ++j)
#pragma unroll
          for (int r = 0; r < 4; ++r)
            Pb[w * 4608 + (i * 16 + q * 4 + r) * 72 + j * 16 + ln] =
                (uint16_t)bf16rn(s2[i][j][r]);
      }
      bf16x8 pa[4][2];
#pragma unroll
      for (int i = 0; i < 4; ++i)
#pragma unroll
        for (int ks = 0; ks < 2; ++ks)
          pa[i][ks] = *(const bf16x8*)&Pb[w * 4608 + (i * 16 + ln) * 72 + ks * 32 + kq];
#pragma unroll
      for (int n = 0; n < 4; ++n) {
        bf16x8 bv0 = *(const bf16x8*)&Vt[(n * 16 + ln) * 72 + kq];
        bf16x8 bv1 = *(const bf16x8*)&Vt[(n * 16 + ln) * 72 + 32 + kq];
#pragma unroll
        for (int i = 0; i < 4; ++i) {
          o_[i][n] = __builtin_amdgcn_mfma_f32_16x16x32_bf16(pa[i][0], bv0, o_[i][n], 0, 0, 0);
          o_[i][n] = __builtin_amdgcn_mfma_f32_16x16x32_bf16(pa[i][1], bv1, o_[i][n], 0, 0, 0);
        }
      }
    }
  }
#pragma unroll
  for (int i = 0; i < 4; ++i) {
    f32x4 lt = l_[i];
#pragma unroll
    for (int off = 1; off < 16; off <<= 1)
#pragma unroll
      for (int r = 0; r < 4; ++r) lt[r] += __shfl_xor(lt[r], off);
#pragma unroll
    for (int r = 0; r < 4; ++r) {
      float inv = 1.0f / lt[r];
      int row = b * T_ + m0 + i * 16 + q * 4 + r;
      uint16_t* op = o + (size_t)row * D_ + h * HDm;
#pragma unroll
      for (int n = 0; n < 4; ++n)
        op[n * 16 + ln] = (uint16_t)bf16rn(o_[i][n][r] * inv);
    }
  }
}

extern "C" void kernel_launch(void* const* d_in, const int* in_sizes, int n_in,
                              void* d_out, int out_size, void* d_ws, size_t ws_size,
                              hipStream_t stream) {
  const float* x   = (const float*)d_in[0];
  const float* Wq  = (const float*)d_in[1];
  const float* Wk  = (const float*)d_in[2];
  const float* Wv  = (const float*)d_in[3];
  const float* Wp  = (const float*)d_in[4];
  const float* bp  = (const float*)d_in[5];
  const float* W1  = (const float*)d_in[6];
  const float* b1  = (const float*)d_in[7];
  const float* W2  = (const float*)d_in[8];
  const float* b2  = (const float*)d_in[9];
  const float* g1  = (const float*)d_in[10];
  const float* be1 = (const float*)d_in[11];
  const float* g2  = (const float*)d_in[12];
  const float* be2 = (const float*)d_in[13];
  float* out = (float*)d_out;

  char* ws = (char*)d_ws;
  uint16_t* hbuf  = (uint16_t*)ws;
  uint16_t* qkv   = (uint16_t*)(ws + 25165824ull);
  uint16_t* ob    = (uint16_t*)(ws + 100663296ull);
  uint16_t* ff1   = qkv;
  uint16_t* Wqkvt = (uint16_t*)(ws + 125829120ull);
  uint16_t* Wpt   = (uint16_t*)(ws + 126713856ull);
  uint16_t* W1t   = (uint16_t*)(ws + 127008768ull);
  uint16_t* W2t   = (uint16_t*)(ws + 128188416ull);

  // 1. pack weights to bf16, K-contiguous
  pack_qkv_w<<<(1152 * D_ + 255) / 256, 256, 0, stream>>>(Wq, Wk, Wv, Wqkvt);
  pack_wt<<<(384 * 384 + 255) / 256, 256, 0, stream>>>(Wp, Wpt, 384, 384);
  pack_wt<<<(384 * 1536 + 255) / 256, 256, 0, stream>>>(W1, W1t, 384, 1536);
  pack_wt<<<(1536 * 384 + 255) / 256, 256, 0, stream>>>(W2, W2t, 1536, 384);
  // 2. LN1: x -> h (bf16)
  ln_kernel<<<NROW, 128, 0, stream>>>(x, g1, be1, hbuf);
  // 3. QKV projection: [32768,384] @ [384,1152] -> bf16  (grid: x=M-tiles(256), y=N-tiles(128))
  gemm_pb<<<dim3(NROW / 256, 1152 / 128), 256, 0, stream>>>(
      hbuf, Wqkvt, nullptr, nullptr, qkv, NROW, 1152, 384, 0, 0);
  // 4. MFMA flash attention -> ob (bf16)
  attn_mfma<<<B_ * Hn, 256, 0, stream>>>(qkv, ob);
  // 5. x1 = x + ob@Wp + bp  -> d_out (fp32)
  gemm_pb<<<dim3(NROW / 256, 384 / 128), 256, 0, stream>>>(
      ob, Wpt, bp, x, out, NROW, 384, 384, 0, 1);
  // 6. LN2: x1 -> h (bf16)
  ln_kernel<<<NROW, 128, 0, stream>>>(out, g2, be2, hbuf);
  // 7. FF1 + ReLU: [32768,384] @ [384,1536] -> bf16
  gemm_pb<<<dim3(NROW / 256, 1536 / 128), 256, 0, stream>>>(
      hbuf, W1t, b1, nullptr, ff1, NROW, 1536, 384, 1, 0);
  // 8. out = x1 + ff1@W2 + b2 -> d_out (fp32)
  gemm_pb<<<dim3(NROW / 256, 384 / 128), 256, 0, stream>>>(
      ff1, W2t, b2, out, out, NROW, 384, 1536, 0, 1);
}

// Round 5
// 613.010 us; speedup vs baseline: 1.6372x; 1.6372x over previous
//
#include <hip/hip_runtime.h>
#include <cstdint>
#include <cstddef>

#define D_   384
#define Hn   6
#define HDm  64
#define T_   256
#define B_   128
#define NROW (B_ * T_)   // 32768

typedef __bf16  bf16x8 __attribute__((ext_vector_type(8)));
typedef float   f32x4  __attribute__((ext_vector_type(4)));
typedef const __attribute__((address_space(1))) void gvoid;
typedef __attribute__((address_space(3))) void lvoid;

// ---------- helpers ----------
__device__ inline uint32_t bf16rn(float f) {
  uint32_t u = __float_as_uint(f);
  return (u + 0x7FFFu + ((u >> 16) & 1u)) >> 16;
}

// ---------- LayerNorm: fp32 in -> bf16 out, one 128-thread block per row ----------
__global__ __launch_bounds__(128) void ln_kernel(const float* __restrict__ x,
                                                 const float* __restrict__ g,
                                                 const float* __restrict__ b,
                                                 uint16_t* __restrict__ out) {
  int row = blockIdx.x, tid = threadIdx.x;
  const float* xr = x + (size_t)row * D_;
  float v0 = xr[tid], v1 = xr[tid + 128], v2 = xr[tid + 256];
  float s  = v0 + v1 + v2;
  float ss = v0 * v0 + v1 * v1 + v2 * v2;
#pragma unroll
  for (int off = 32; off > 0; off >>= 1) {
    s  += __shfl_down(s, off);
    ss += __shfl_down(ss, off);
  }
  __shared__ float red[4];
  if ((tid & 63) == 0) { red[(tid >> 6) * 2] = s; red[(tid >> 6) * 2 + 1] = ss; }
  __syncthreads();
  float S = red[0] + red[2], SS = red[1] + red[3];
  float mu  = S * (1.0f / D_);
  float var = SS * (1.0f / D_) - mu * mu;
  float inv = rsqrtf(var + 1e-5f);
  uint16_t* orow = out + (size_t)row * D_;
  orow[tid]       = (uint16_t)bf16rn((v0 - mu) * inv * g[tid]       + b[tid]);
  orow[tid + 128] = (uint16_t)bf16rn((v1 - mu) * inv * g[tid + 128] + b[tid + 128]);
  orow[tid + 256] = (uint16_t)bf16rn((v2 - mu) * inv * g[tid + 256] + b[tid + 256]);
}

// ---------- merged weight pack: all four weight tensors in one launch ----------
// [0, 442368)            : Wq/Wk/Wv [H,D,HD] -> Wqkvt[col=1152][d=384]
// [442368, 589824)       : Wp  [384,384]   -> Wpt[384][384]
// [589824, 1179648)      : W1  [384,1536]  -> W1t[1536][384]
// [1179648, 1769472)     : W2  [1536,384]  -> W2t[384][1536]
__global__ __launch_bounds__(256) void pack_all(const float* __restrict__ Wq,
                                                const float* __restrict__ Wk,
                                                const float* __restrict__ Wv,
                                                const float* __restrict__ Wp,
                                                const float* __restrict__ W1,
                                                const float* __restrict__ W2,
                                                uint16_t* __restrict__ Wqkvt,
                                                uint16_t* __restrict__ Wpt,
                                                uint16_t* __restrict__ W1t,
                                                uint16_t* __restrict__ W2t) {
  int idx = blockIdx.x * 256 + threadIdx.x;
  if (idx < 442368) {
    int col = idx / D_, d = idx % D_;
    int which = col / 384, c2 = col % 384;
    int h = c2 / HDm, k = c2 % HDm;
    const float* W = (which == 0) ? Wq : (which == 1) ? Wk : Wv;
    Wqkvt[idx] = (uint16_t)bf16rn(W[((size_t)h * D_ + d) * HDm + k]);
    return;
  }
  int i2 = idx - 442368;
  if (i2 < 147456) {
    int n = i2 / 384, k = i2 % 384;
    Wpt[i2] = (uint16_t)bf16rn(Wp[(size_t)k * 384 + n]);
    return;
  }
  int i3 = i2 - 147456;
  if (i3 < 589824) {
    int n = i3 / 384, k = i3 % 384;
    W1t[i3] = (uint16_t)bf16rn(W1[(size_t)k * 1536 + n]);
    return;
  }
  int i4 = i3 - 589824;
  if (i4 < 589824) {
    int n = i4 / 1536, k = i4 % 1536;
    W2t[i4] = (uint16_t)bf16rn(W2[(size_t)k * 384 + n]);
  }
}

// ---------- bf16 MFMA GEMM: C[M,N] = A[M,K] @ Bt[N,K]^T (+bias)(relu)(+resid) ----------
// r0-proven structure, BK widened 32 -> 64: 128x128 tile, 4 waves, 4x4
// mfma_f32_16x16x32_bf16 per wave per 32-K half (32 MFMA per K-step).
// DOUBLE-BUFFERED: prefetch tile i+1 via global_load_lds right after the
// barrier, compute tile i meanwhile. One __syncthreads per K-step; K-steps
// halved vs BK=32 so the per-step fixed cost (barrier skew + vmcnt drain +
// staging issue) is paid 6x not 12x per block (K=384).
// Row = 64 bf16 = 128 B = exact 32-bank wrap, so chunk c (16 B) is stored and
// read at c ^ (row&7) (both-sides swizzle, verified 0-conflict in r3).
// Requires K%64==0 (384, 1536 comply).
__global__ __launch_bounds__(256) void gemm_bf16(const uint16_t* __restrict__ A,
                                                 const uint16_t* __restrict__ Bt,
                                                 const float* __restrict__ bias,
                                                 const float* __restrict__ resid,
                                                 void* __restrict__ Cout,
                                                 int M, int N, int K,
                                                 int relu, int store_f32) {
  __shared__ uint16_t As[2][128 * 64];   // 2 x 16 KB
  __shared__ uint16_t Bs[2][128 * 64];   // 2 x 16 KB
  int tid = threadIdx.x;
  int bm = blockIdx.x * 128, bn = blockIdx.y * 128;
  int lane = tid & 63, wave = tid >> 6;
  int wm = (wave >> 1) << 6;
  int wn = (wave & 1) << 6;
  int lr = lane & 15;                 // row-within-16
  int q  = lane >> 4;                 // k-chunk selector (0..3)
  int r0 = q << 2;                    // C row base within 16
  int rd0 = ((q       ^ (lr & 7)) << 3);   // ks=0 swizzled elem offset in row
  int rd1 = (((4 | q) ^ (lr & 7)) << 3);   // ks=1

  // staging: 1024 chunks of 16 B per operand per buffer -> 4 chunks/thread each
  // chunk ch: row = ch>>3, slot = ch&7 (= tid&7 since stride 256); source data
  // is logical chunk (slot ^ (row&7)) -> pre-swizzled global column.
  const uint16_t* ga[4];
  const uint16_t* gb[4];
  int ld[4];
#pragma unroll
  for (int t = 0; t < 4; ++t) {
    int ch  = tid + t * 256;
    int row = ch >> 3;
    int col = ((tid & 7) ^ (row & 7)) << 3;
    ga[t] = A  + (size_t)(bm + row) * K + col;
    gb[t] = Bt + (size_t)(bn + row) * K + col;
    ld[t] = ch * 16;
  }

  f32x4 acc[4][4];
  const f32x4 zero = {0.f, 0.f, 0.f, 0.f};
#pragma unroll
  for (int i = 0; i < 4; ++i)
#pragma unroll
    for (int j = 0; j < 4; ++j) acc[i][j] = zero;

#define STAGE(bi_, kt_)                                                                        \
  {                                                                                            \
    int ko_ = (kt_) << 6;                                                                      \
    _Pragma("unroll")                                                                          \
    for (int t_ = 0; t_ < 4; ++t_) {                                                           \
      __builtin_amdgcn_global_load_lds((gvoid*)(ga[t_] + ko_), (lvoid*)((char*)As[bi_] + ld[t_]), 16, 0, 0); \
      __builtin_amdgcn_global_load_lds((gvoid*)(gb[t_] + ko_), (lvoid*)((char*)Bs[bi_] + ld[t_]), 16, 0, 0); \
    }                                                                                          \
  }

  int nk = K >> 6;                    // 6 (K=384) or 24 (K=1536)
  STAGE(0, 0)

  for (int i = 0; i < nk; ++i) {
    int cur = i & 1;
    __syncthreads();     // drains vmcnt -> buf[cur] staged; prior reads of buf[cur^1] done
    if (i + 1 < nk) STAGE(cur ^ 1, i + 1)

#pragma unroll
    for (int ks = 0; ks < 2; ++ks) {
      int ro = ks ? rd1 : rd0;
      bf16x8 af[4], bfr[4];
#pragma unroll
      for (int ii = 0; ii < 4; ++ii)
        af[ii] = *(const bf16x8*)&As[cur][(wm + ii * 16 + lr) * 64 + ro];
#pragma unroll
      for (int j = 0; j < 4; ++j)
        bfr[j] = *(const bf16x8*)&Bs[cur][(wn + j * 16 + lr) * 64 + ro];
#pragma unroll
      for (int ii = 0; ii < 4; ++ii)
#pragma unroll
        for (int j = 0; j < 4; ++j)
          acc[ii][j] = __builtin_amdgcn_mfma_f32_16x16x32_bf16(af[ii], bfr[j], acc[ii][j], 0, 0, 0);
    }
  }
#undef STAGE

#pragma unroll
  for (int i = 0; i < 4; ++i) {
#pragma unroll
    for (int r = 0; r < 4; ++r) {
      int rr = bm + wm + i * 16 + r0 + r;
#pragma unroll
      for (int j = 0; j < 4; ++j) {
        int col = bn + wn + j * 16 + lr;
        float v = acc[i][j][r];
        if (bias)  v += bias[col];
        if (relu)  v = fmaxf(v, 0.0f);
        if (resid) v += resid[(size_t)rr * N + col];
        if (store_f32) ((float*)Cout)[(size_t)rr * N + col] = v;
        else           ((uint16_t*)Cout)[(size_t)rr * N + col] = (uint16_t)bf16rn(v);
      }
    }
  }
}

// ---------- MFMA flash attention: one block per (b,h), 4 waves, wave w = rows w*64..w*64+63 ----------
// qkv (bf16) row (b*T+t): cols [0,384)=q(h*64+d), [384,768)=k, [768,1152)=v
__global__ __launch_bounds__(256, 2) void attn_mfma(const uint16_t* __restrict__ qkv,
                                                    uint16_t* __restrict__ o) {
  __shared__ uint16_t Kt[64 * 72];        // K-tile [s][d], pad 72 (9216 B)
  __shared__ uint16_t Vt[64 * 72];        // V-tile transposed [d][s], pad 72 (9216 B)
  __shared__ uint16_t Pb[4 * 64 * 72];    // per-wave P staging (36864 B)
  int bh = blockIdx.x;
  int b = bh / Hn, h = bh % Hn;
  int tid = threadIdx.x;
  int lane = tid & 63, w = tid >> 6;
  int ln = lane & 15, q = lane >> 4;
  int kq = q * 8;
  int m0 = w * 64;
  const uint16_t* base = qkv + (size_t)b * T_ * 1152;

  bf16x8 af[4][2];
#pragma unroll
  for (int i = 0; i < 4; ++i)
#pragma unroll
    for (int ks = 0; ks < 2; ++ks)
      af[i][ks] = *(const bf16x8*)(base + (size_t)(m0 + i * 16 + ln) * 1152 + h * HDm + ks * 32 + kq);

  f32x4 o_[4][4], m_[4], l_[4];
  const f32x4 zero = {0.f, 0.f, 0.f, 0.f};
#pragma unroll
  for (int i = 0; i < 4; ++i) {
    m_[i] = {-1e30f, -1e30f, -1e30f, -1e30f};
    l_[i] = zero;
#pragma unroll
    for (int n = 0; n < 4; ++n) o_[i][n] = zero;
  }
  const float cs = 0.07362222f;  // (1/sqrt(384)) * log2(e)

  for (int jt = 0; jt < 4; ++jt) {
    if (jt) __syncthreads();
#pragma unroll
    for (int t = 0; t < 2; ++t) {
      int c = t * 256 + tid;
      int s = c >> 3, d0 = (c & 7) << 3;
      *(uint4*)&Kt[s * 72 + d0] =
          *(const uint4*)(base + (size_t)(jt * 64 + s) * 1152 + 384 + h * HDm + d0);
    }
    {
      int sv = tid & 63, dv = (tid >> 6) << 4;
      const uint16_t* gv = base + (size_t)(jt * 64 + sv) * 1152 + 768 + h * HDm + dv;
      uint16_t tmp[16];
      *(uint4*)&tmp[0] = *(const uint4*)gv;
      *(uint4*)&tmp[8] = *(const uint4*)(gv + 8);
#pragma unroll
      for (int jj = 0; jj < 16; ++jj) Vt[(dv + jj) * 72 + sv] = tmp[jj];
    }
    __syncthreads();

    if (w >= jt) {
      f32x4 s2[4][4];
#pragma unroll
      for (int i = 0; i < 4; ++i)
#pragma unroll
        for (int j = 0; j < 4; ++j) s2[i][j] = zero;
#pragma unroll
      for (int ks = 0; ks < 2; ++ks) {
        bf16x8 bf[4];
#pragma unroll
        for (int j = 0; j < 4; ++j)
          bf[j] = *(const bf16x8*)&Kt[(j * 16 + ln) * 72 + ks * 32 + kq];
#pragma unroll
        for (int i = 0; i < 4; ++i)
#pragma unroll
          for (int j = 0; j < 4; ++j)
            s2[i][j] = __builtin_amdgcn_mfma_f32_16x16x32_bf16(af[i][ks], bf[j], s2[i][j], 0, 0, 0);
      }
#pragma unroll
      for (int i = 0; i < 4; ++i) {
#pragma unroll
        for (int j = 0; j < 4; ++j)
#pragma unroll
          for (int r = 0; r < 4; ++r) s2[i][j][r] *= cs;
        if (jt == w) {
#pragma unroll
          for (int j = 0; j < 4; ++j)
#pragma unroll
            for (int r = 0; r < 4; ++r)
              if (j * 16 + ln > i * 16 + q * 4 + r) s2[i][j][r] = -1e30f;
        }
        f32x4 rm;
#pragma unroll
        for (int r = 0; r < 4; ++r)
          rm[r] = fmaxf(fmaxf(s2[i][0][r], s2[i][1][r]), fmaxf(s2[i][2][r], s2[i][3][r]));
#pragma unroll
        for (int off = 1; off < 16; off <<= 1)
#pragma unroll
          for (int r = 0; r < 4; ++r)
            rm[r] = fmaxf(rm[r], __shfl_xor(rm[r], off));
        f32x4 mn, al, ps;
#pragma unroll
        for (int r = 0; r < 4; ++r) {
          mn[r] = fmaxf(m_[i][r], rm[r]);
          al[r] = exp2f(m_[i][r] - mn[r]);
          ps[r] = 0.f;
        }
        m_[i] = mn;
#pragma unroll
        for (int j = 0; j < 4; ++j)
#pragma unroll
          for (int r = 0; r < 4; ++r) {
            float p = exp2f(s2[i][j][r] - mn[r]);
            s2[i][j][r] = p;
            ps[r] += p;
          }
#pragma unroll
        for (int r = 0; r < 4; ++r) l_[i][r] = l_[i][r] * al[r] + ps[r];
#pragma unroll
        for (int n = 0; n < 4; ++n)
#pragma unroll
          for (int r = 0; r < 4; ++r) o_[i][n][r] *= al[r];
#pragma unroll
        for (int j = 0; j < 4; ++j)
#pragma unroll
          for (int r = 0; r < 4; ++r)
            Pb[w * 4608 + (i * 16 + q * 4 + r) * 72 + j * 16 + ln] =
                (uint16_t)bf16rn(s2[i][j][r]);
      }
      bf16x8 pa[4][2];
#pragma unroll
      for (int i = 0; i < 4; ++i)
#pragma unroll
        for (int ks = 0; ks < 2; ++ks)
          pa[i][ks] = *(const bf16x8*)&Pb[w * 4608 + (i * 16 + ln) * 72 + ks * 32 + kq];
#pragma unroll
      for (int n = 0; n < 4; ++n) {
        bf16x8 bv0 = *(const bf16x8*)&Vt[(n * 16 + ln) * 72 + kq];
        bf16x8 bv1 = *(const bf16x8*)&Vt[(n * 16 + ln) * 72 + 32 + kq];
#pragma unroll
        for (int i = 0; i < 4; ++i) {
          o_[i][n] = __builtin_amdgcn_mfma_f32_16x16x32_bf16(pa[i][0], bv0, o_[i][n], 0, 0, 0);
          o_[i][n] = __builtin_amdgcn_mfma_f32_16x16x32_bf16(pa[i][1], bv1, o_[i][n], 0, 0, 0);
        }
      }
    }
  }
#pragma unroll
  for (int i = 0; i < 4; ++i) {
    f32x4 lt = l_[i];
#pragma unroll
    for (int off = 1; off < 16; off <<= 1)
#pragma unroll
      for (int r = 0; r < 4; ++r) lt[r] += __shfl_xor(lt[r], off);
#pragma unroll
    for (int r = 0; r < 4; ++r) {
      float inv = 1.0f / lt[r];
      int row = b * T_ + m0 + i * 16 + q * 4 + r;
      uint16_t* op = o + (size_t)row * D_ + h * HDm;
#pragma unroll
      for (int n = 0; n < 4; ++n)
        op[n * 16 + ln] = (uint16_t)bf16rn(o_[i][n][r] * inv);
    }
  }
}

extern "C" void kernel_launch(void* const* d_in, const int* in_sizes, int n_in,
                              void* d_out, int out_size, void* d_ws, size_t ws_size,
                              hipStream_t stream) {
  const float* x   = (const float*)d_in[0];
  const float* Wq  = (const float*)d_in[1];
  const float* Wk  = (const float*)d_in[2];
  const float* Wv  = (const float*)d_in[3];
  const float* Wp  = (const float*)d_in[4];
  const float* bp  = (const float*)d_in[5];
  const float* W1  = (const float*)d_in[6];
  const float* b1  = (const float*)d_in[7];
  const float* W2  = (const float*)d_in[8];
  const float* b2  = (const float*)d_in[9];
  const float* g1  = (const float*)d_in[10];
  const float* be1 = (const float*)d_in[11];
  const float* g2  = (const float*)d_in[12];
  const float* be2 = (const float*)d_in[13];
  float* out = (float*)d_out;

  char* ws = (char*)d_ws;
  uint16_t* hbuf  = (uint16_t*)ws;
  uint16_t* qkv   = (uint16_t*)(ws + 25165824ull);
  uint16_t* ob    = (uint16_t*)(ws + 100663296ull);
  uint16_t* ff1   = qkv;
  uint16_t* Wqkvt = (uint16_t*)(ws + 125829120ull);
  uint16_t* Wpt   = (uint16_t*)(ws + 126713856ull);
  uint16_t* W1t   = (uint16_t*)(ws + 127008768ull);
  uint16_t* W2t   = (uint16_t*)(ws + 128188416ull);

  // 1. pack all weights to bf16, K-contiguous (single launch)
  pack_all<<<6912, 256, 0, stream>>>(Wq, Wk, Wv, Wp, W1, W2, Wqkvt, Wpt, W1t, W2t);
  // 2. LN1: x -> h (bf16)
  ln_kernel<<<NROW, 128, 0, stream>>>(x, g1, be1, hbuf);
  // 3. QKV projection: [32768,384] @ [384,1152] -> bf16   (grid: x=M-tiles, y=N-tiles)
  gemm_bf16<<<dim3(NROW / 128, 1152 / 128), 256, 0, stream>>>(
      hbuf, Wqkvt, nullptr, nullptr, qkv, NROW, 1152, 384, 0, 0);
  // 4. MFMA flash attention -> ob (bf16)
  attn_mfma<<<B_ * Hn, 256, 0, stream>>>(qkv, ob);
  // 5. x1 = x + ob@Wp + bp  -> d_out (fp32)
  gemm_bf16<<<dim3(NROW / 128, 384 / 128), 256, 0, stream>>>(
      ob, Wpt, bp, x, out, NROW, 384, 384, 0, 1);
  // 6. LN2: x1 -> h (bf16)
  ln_kernel<<<NROW, 128, 0, stream>>>(out, g2, be2, hbuf);
  // 7. FF1 + ReLU: [32768,384] @ [384,1536] -> bf16
  gemm_bf16<<<dim3(NROW / 128, 1536 / 128), 256, 0, stream>>>(
      hbuf, W1t, b1, nullptr, ff1, NROW, 1536, 384, 1, 0);
  // 8. out = x1 + ff1@W2 + b2 -> d_out (fp32)
  gemm_bf16<<<dim3(NROW / 128, 384 / 128), 256, 0, stream>>>(
      ff1, W2t, b2, out, out, NROW, 384, 1536, 0, 1);
}

// Round 6
// 490.472 us; speedup vs baseline: 2.0462x; 1.2498x over previous
//
#include <hip/hip_runtime.h>
#include <cstdint>
#include <cstddef>

#define D_   384
#define Hn   6
#define HDm  64
#define T_   256
#define B_   128
#define NROW (B_ * T_)   // 32768

typedef __bf16  bf16x8 __attribute__((ext_vector_type(8)));
typedef float   f32x4  __attribute__((ext_vector_type(4)));
typedef const __attribute__((address_space(1))) void gvoid;
typedef __attribute__((address_space(3))) void lvoid;

// ---------- helpers ----------
__device__ inline uint32_t bf16rn(float f) {
  uint32_t u = __float_as_uint(f);
  return (u + 0x7FFFu + ((u >> 16) & 1u)) >> 16;
}

// ---------- LayerNorm: fp32 in -> bf16 out, one 128-thread block per row ----------
__global__ __launch_bounds__(128) void ln_kernel(const float* __restrict__ x,
                                                 const float* __restrict__ g,
                                                 const float* __restrict__ b,
                                                 uint16_t* __restrict__ out) {
  int row = blockIdx.x, tid = threadIdx.x;
  const float* xr = x + (size_t)row * D_;
  float v0 = xr[tid], v1 = xr[tid + 128], v2 = xr[tid + 256];
  float s  = v0 + v1 + v2;
  float ss = v0 * v0 + v1 * v1 + v2 * v2;
#pragma unroll
  for (int off = 32; off > 0; off >>= 1) {
    s  += __shfl_down(s, off);
    ss += __shfl_down(ss, off);
  }
  __shared__ float red[4];
  if ((tid & 63) == 0) { red[(tid >> 6) * 2] = s; red[(tid >> 6) * 2 + 1] = ss; }
  __syncthreads();
  float S = red[0] + red[2], SS = red[1] + red[3];
  float mu  = S * (1.0f / D_);
  float var = SS * (1.0f / D_) - mu * mu;
  float inv = rsqrtf(var + 1e-5f);
  uint16_t* orow = out + (size_t)row * D_;
  orow[tid]       = (uint16_t)bf16rn((v0 - mu) * inv * g[tid]       + b[tid]);
  orow[tid + 128] = (uint16_t)bf16rn((v1 - mu) * inv * g[tid + 128] + b[tid + 128]);
  orow[tid + 256] = (uint16_t)bf16rn((v2 - mu) * inv * g[tid + 256] + b[tid + 256]);
}

// ---------- merged weight pack: all four weight tensors in one launch ----------
__global__ __launch_bounds__(256) void pack_all(const float* __restrict__ Wq,
                                                const float* __restrict__ Wk,
                                                const float* __restrict__ Wv,
                                                const float* __restrict__ Wp,
                                                const float* __restrict__ W1,
                                                const float* __restrict__ W2,
                                                uint16_t* __restrict__ Wqkvt,
                                                uint16_t* __restrict__ Wpt,
                                                uint16_t* __restrict__ W1t,
                                                uint16_t* __restrict__ W2t) {
  int idx = blockIdx.x * 256 + threadIdx.x;
  if (idx < 442368) {
    int col = idx / D_, d = idx % D_;
    int which = col / 384, c2 = col % 384;
    int h = c2 / HDm, k = c2 % HDm;
    const float* W = (which == 0) ? Wq : (which == 1) ? Wk : Wv;
    Wqkvt[idx] = (uint16_t)bf16rn(W[((size_t)h * D_ + d) * HDm + k]);
    return;
  }
  int i2 = idx - 442368;
  if (i2 < 147456) {
    int n = i2 / 384, k = i2 % 384;
    Wpt[i2] = (uint16_t)bf16rn(Wp[(size_t)k * 384 + n]);
    return;
  }
  int i3 = i2 - 147456;
  if (i3 < 589824) {
    int n = i3 / 384, k = i3 % 384;
    W1t[i3] = (uint16_t)bf16rn(W1[(size_t)k * 1536 + n]);
    return;
  }
  int i4 = i3 - 589824;
  if (i4 < 589824) {
    int n = i4 / 1536, k = i4 % 1536;
    W2t[i4] = (uint16_t)bf16rn(W2[(size_t)k * 384 + n]);
  }
}

// ---------- bf16 MFMA GEMM: C[M,N] = A[M,K] @ Bt[N,K]^T (+bias)(relu)(+resid) ----------
// OCCUPANCY-FIRST variant of the r0-proven structure (dur*occ invariant: the
// kernel is latency-bound; resident waves are the only lever that has moved it).
// 128x64 tile, BK=32, 4 waves, wave tile 32x64 (2x4 mfma_f32_16x16x32_bf16).
// acc = 32 AGPR (was 64), frags 24 VGPR, LDS 24 KB (was 32) -> with
// __launch_bounds__(256,6) (reg cap 85) target 6 blocks/CU = 24 waves = 75% occ
// (was 3 waves/SIMD / 31%). Same 2-buffer __syncthreads pipeline, same
// both-sides chunk swizzle (chunk c of row r stored/read at c^(r&3)) as r0.
// Requires K%32==0, M%128==0, N%64==0 (all shapes comply).
__global__ __launch_bounds__(256, 6) void gemm_bf16(const uint16_t* __restrict__ A,
                                                    const uint16_t* __restrict__ Bt,
                                                    const float* __restrict__ bias,
                                                    const float* __restrict__ resid,
                                                    void* __restrict__ Cout,
                                                    int M, int N, int K,
                                                    int relu, int store_f32) {
  __shared__ uint16_t As[2][128 * 32];   // 2 x 8 KB
  __shared__ uint16_t Bs[2][64 * 32];    // 2 x 4 KB
  int tid = threadIdx.x;
  int bm = blockIdx.x * 128, bn = blockIdx.y * 64;
  int lane = tid & 63, wave = tid >> 6;
  int wm = wave << 5;                 // 32 rows per wave
  int lr = lane & 15;                 // row-within-16
  int q  = lane >> 4;                 // k-chunk selector (0..3)
  int r0 = q << 2;                    // C row base within 16
  int rd_off = (q ^ (lr & 3)) << 3;   // swizzled chunk elem offset within row

  // staging: A-tile 512 chunks of 16B (2/thread), B-tile 256 chunks (1/thread)
  // chunk ch: row = ch>>2, slot = ch&3; global source = logical chunk slot^(row&3)
  int rowA = tid >> 2;                // 0..63 (A also rowA+64; B uses rowA)
  int slot = tid & 3;
  int gcol = (slot ^ (rowA & 3)) << 3;   // (rowA+64)&3 == rowA&3
  const uint16_t* ga0 = A  + (size_t)(bm + rowA) * K + gcol;
  const uint16_t* ga1 = A  + (size_t)(bm + rowA + 64) * K + gcol;
  const uint16_t* gb0 = Bt + (size_t)(bn + rowA) * K + gcol;

  f32x4 acc[2][4];
  const f32x4 zero = {0.f, 0.f, 0.f, 0.f};
#pragma unroll
  for (int i = 0; i < 2; ++i)
#pragma unroll
    for (int j = 0; j < 4; ++j) acc[i][j] = zero;

#define STAGE(bi_, kt_)                                                                        \
  {                                                                                            \
    int ko_ = (kt_) << 5;                                                                      \
    __builtin_amdgcn_global_load_lds((gvoid*)(ga0 + ko_), (lvoid*)((char*)As[bi_] + tid * 16), 16, 0, 0);          \
    __builtin_amdgcn_global_load_lds((gvoid*)(ga1 + ko_), (lvoid*)((char*)As[bi_] + tid * 16 + 4096), 16, 0, 0);   \
    __builtin_amdgcn_global_load_lds((gvoid*)(gb0 + ko_), (lvoid*)((char*)Bs[bi_] + tid * 16), 16, 0, 0);          \
  }

  int nk = K >> 5;                    // 12 (K=384) or 48 (K=1536)
  STAGE(0, 0)

  for (int i = 0; i < nk; ++i) {
    int cur = i & 1;
    __syncthreads();     // drains vmcnt -> buf[cur] staged; prior reads of buf[cur^1] done
    if (i + 1 < nk) STAGE(cur ^ 1, i + 1)

    bf16x8 af[2], bfr[4];
#pragma unroll
    for (int ii = 0; ii < 2; ++ii)
      af[ii] = *(const bf16x8*)&As[cur][(wm + ii * 16 + lr) * 32 + rd_off];
#pragma unroll
    for (int j = 0; j < 4; ++j)
      bfr[j] = *(const bf16x8*)&Bs[cur][(j * 16 + lr) * 32 + rd_off];
#pragma unroll
    for (int ii = 0; ii < 2; ++ii)
#pragma unroll
      for (int j = 0; j < 4; ++j)
        acc[ii][j] = __builtin_amdgcn_mfma_f32_16x16x32_bf16(af[ii], bfr[j], acc[ii][j], 0, 0, 0);
  }
#undef STAGE

#pragma unroll
  for (int i = 0; i < 2; ++i) {
#pragma unroll
    for (int r = 0; r < 4; ++r) {
      int rr = bm + wm + i * 16 + r0 + r;
#pragma unroll
      for (int j = 0; j < 4; ++j) {
        int col = bn + j * 16 + lr;
        float v = acc[i][j][r];
        if (bias)  v += bias[col];
        if (relu)  v = fmaxf(v, 0.0f);
        if (resid) v += resid[(size_t)rr * N + col];
        if (store_f32) ((float*)Cout)[(size_t)rr * N + col] = v;
        else           ((uint16_t*)Cout)[(size_t)rr * N + col] = (uint16_t)bf16rn(v);
      }
    }
  }
}

// ---------- MFMA flash attention: one block per (b,h), 4 waves, wave w = rows w*64..w*64+63 ----------
// qkv (bf16) row (b*T+t): cols [0,384)=q(h*64+d), [384,768)=k, [768,1152)=v
__global__ __launch_bounds__(256, 2) void attn_mfma(const uint16_t* __restrict__ qkv,
                                                    uint16_t* __restrict__ o) {
  __shared__ uint16_t Kt[64 * 72];        // K-tile [s][d], pad 72 (9216 B)
  __shared__ uint16_t Vt[64 * 72];        // V-tile transposed [d][s], pad 72 (9216 B)
  __shared__ uint16_t Pb[4 * 64 * 72];    // per-wave P staging (36864 B)
  int bh = blockIdx.x;
  int b = bh / Hn, h = bh % Hn;
  int tid = threadIdx.x;
  int lane = tid & 63, w = tid >> 6;
  int ln = lane & 15, q = lane >> 4;
  int kq = q * 8;
  int m0 = w * 64;
  const uint16_t* base = qkv + (size_t)b * T_ * 1152;

  bf16x8 af[4][2];
#pragma unroll
  for (int i = 0; i < 4; ++i)
#pragma unroll
    for (int ks = 0; ks < 2; ++ks)
      af[i][ks] = *(const bf16x8*)(base + (size_t)(m0 + i * 16 + ln) * 1152 + h * HDm + ks * 32 + kq);

  f32x4 o_[4][4], m_[4], l_[4];
  const f32x4 zero = {0.f, 0.f, 0.f, 0.f};
#pragma unroll
  for (int i = 0; i < 4; ++i) {
    m_[i] = {-1e30f, -1e30f, -1e30f, -1e30f};
    l_[i] = zero;
#pragma unroll
    for (int n = 0; n < 4; ++n) o_[i][n] = zero;
  }
  const float cs = 0.07362222f;  // (1/sqrt(384)) * log2(e)

  for (int jt = 0; jt < 4; ++jt) {
    if (jt) __syncthreads();
#pragma unroll
    for (int t = 0; t < 2; ++t) {
      int c = t * 256 + tid;
      int s = c >> 3, d0 = (c & 7) << 3;
      *(uint4*)&Kt[s * 72 + d0] =
          *(const uint4*)(base + (size_t)(jt * 64 + s) * 1152 + 384 + h * HDm + d0);
    }
    {
      int sv = tid & 63, dv = (tid >> 6) << 4;
      const uint16_t* gv = base + (size_t)(jt * 64 + sv) * 1152 + 768 + h * HDm + dv;
      uint16_t tmp[16];
      *(uint4*)&tmp[0] = *(const uint4*)gv;
      *(uint4*)&tmp[8] = *(const uint4*)(gv + 8);
#pragma unroll
      for (int jj = 0; jj < 16; ++jj) Vt[(dv + jj) * 72 + sv] = tmp[jj];
    }
    __syncthreads();

    if (w >= jt) {
      f32x4 s2[4][4];
#pragma unroll
      for (int i = 0; i < 4; ++i)
#pragma unroll
        for (int j = 0; j < 4; ++j) s2[i][j] = zero;
#pragma unroll
      for (int ks = 0; ks < 2; ++ks) {
        bf16x8 bf[4];
#pragma unroll
        for (int j = 0; j < 4; ++j)
          bf[j] = *(const bf16x8*)&Kt[(j * 16 + ln) * 72 + ks * 32 + kq];
#pragma unroll
        for (int i = 0; i < 4; ++i)
#pragma unroll
          for (int j = 0; j < 4; ++j)
            s2[i][j] = __builtin_amdgcn_mfma_f32_16x16x32_bf16(af[i][ks], bf[j], s2[i][j], 0, 0, 0);
      }
#pragma unroll
      for (int i = 0; i < 4; ++i) {
#pragma unroll
        for (int j = 0; j < 4; ++j)
#pragma unroll
          for (int r = 0; r < 4; ++r) s2[i][j][r] *= cs;
        if (jt == w) {
#pragma unroll
          for (int j = 0; j < 4; ++j)
#pragma unroll
            for (int r = 0; r < 4; ++r)
              if (j * 16 + ln > i * 16 + q * 4 + r) s2[i][j][r] = -1e30f;
        }
        f32x4 rm;
#pragma unroll
        for (int r = 0; r < 4; ++r)
          rm[r] = fmaxf(fmaxf(s2[i][0][r], s2[i][1][r]), fmaxf(s2[i][2][r], s2[i][3][r]));
#pragma unroll
        for (int off = 1; off < 16; off <<= 1)
#pragma unroll
          for (int r = 0; r < 4; ++r)
            rm[r] = fmaxf(rm[r], __shfl_xor(rm[r], off));
        f32x4 mn, al, ps;
#pragma unroll
        for (int r = 0; r < 4; ++r) {
          mn[r] = fmaxf(m_[i][r], rm[r]);
          al[r] = exp2f(m_[i][r] - mn[r]);
          ps[r] = 0.f;
        }
        m_[i] = mn;
#pragma unroll
        for (int j = 0; j < 4; ++j)
#pragma unroll
          for (int r = 0; r < 4; ++r) {
            float p = exp2f(s2[i][j][r] - mn[r]);
            s2[i][j][r] = p;
            ps[r] += p;
          }
#pragma unroll
        for (int r = 0; r < 4; ++r) l_[i][r] = l_[i][r] * al[r] + ps[r];
#pragma unroll
        for (int n = 0; n < 4; ++n)
#pragma unroll
          for (int r = 0; r < 4; ++r) o_[i][n][r] *= al[r];
#pragma unroll
        for (int j = 0; j < 4; ++j)
#pragma unroll
          for (int r = 0; r < 4; ++r)
            Pb[w * 4608 + (i * 16 + q * 4 + r) * 72 + j * 16 + ln] =
                (uint16_t)bf16rn(s2[i][j][r]);
      }
      bf16x8 pa[4][2];
#pragma unroll
      for (int i = 0; i < 4; ++i)
#pragma unroll
        for (int ks = 0; ks < 2; ++ks)
          pa[i][ks] = *(const bf16x8*)&Pb[w * 4608 + (i * 16 + ln) * 72 + ks * 32 + kq];
#pragma unroll
      for (int n = 0; n < 4; ++n) {
        bf16x8 bv0 = *(const bf16x8*)&Vt[(n * 16 + ln) * 72 + kq];
        bf16x8 bv1 = *(const bf16x8*)&Vt[(n * 16 + ln) * 72 + 32 + kq];
#pragma unroll
        for (int i = 0; i < 4; ++i) {
          o_[i][n] = __builtin_amdgcn_mfma_f32_16x16x32_bf16(pa[i][0], bv0, o_[i][n], 0, 0, 0);
          o_[i][n] = __builtin_amdgcn_mfma_f32_16x16x32_bf16(pa[i][1], bv1, o_[i][n], 0, 0, 0);
        }
      }
    }
  }
#pragma unroll
  for (int i = 0; i < 4; ++i) {
    f32x4 lt = l_[i];
#pragma unroll
    for (int off = 1; off < 16; off <<= 1)
#pragma unroll
      for (int r = 0; r < 4; ++r) lt[r] += __shfl_xor(lt[r], off);
#pragma unroll
    for (int r = 0; r < 4; ++r) {
      float inv = 1.0f / lt[r];
      int row = b * T_ + m0 + i * 16 + q * 4 + r;
      uint16_t* op = o + (size_t)row * D_ + h * HDm;
#pragma unroll
      for (int n = 0; n < 4; ++n)
        op[n * 16 + ln] = (uint16_t)bf16rn(o_[i][n][r] * inv);
    }
  }
}

extern "C" void kernel_launch(void* const* d_in, const int* in_sizes, int n_in,
                              void* d_out, int out_size, void* d_ws, size_t ws_size,
                              hipStream_t stream) {
  const float* x   = (const float*)d_in[0];
  const float* Wq  = (const float*)d_in[1];
  const float* Wk  = (const float*)d_in[2];
  const float* Wv  = (const float*)d_in[3];
  const float* Wp  = (const float*)d_in[4];
  const float* bp  = (const float*)d_in[5];
  const float* W1  = (const float*)d_in[6];
  const float* b1  = (const float*)d_in[7];
  const float* W2  = (const float*)d_in[8];
  const float* b2  = (const float*)d_in[9];
  const float* g1  = (const float*)d_in[10];
  const float* be1 = (const float*)d_in[11];
  const float* g2  = (const float*)d_in[12];
  const float* be2 = (const float*)d_in[13];
  float* out = (float*)d_out;

  char* ws = (char*)d_ws;
  uint16_t* hbuf  = (uint16_t*)ws;
  uint16_t* qkv   = (uint16_t*)(ws + 25165824ull);
  uint16_t* ob    = (uint16_t*)(ws + 100663296ull);
  uint16_t* ff1   = qkv;
  uint16_t* Wqkvt = (uint16_t*)(ws + 125829120ull);
  uint16_t* Wpt   = (uint16_t*)(ws + 126713856ull);
  uint16_t* W1t   = (uint16_t*)(ws + 127008768ull);
  uint16_t* W2t   = (uint16_t*)(ws + 128188416ull);

  // 1. pack all weights to bf16, K-contiguous (single launch)
  pack_all<<<6912, 256, 0, stream>>>(Wq, Wk, Wv, Wp, W1, W2, Wqkvt, Wpt, W1t, W2t);
  // 2. LN1: x -> h (bf16)
  ln_kernel<<<NROW, 128, 0, stream>>>(x, g1, be1, hbuf);
  // 3. QKV projection: [32768,384] @ [384,1152] -> bf16   (grid: x=M-tiles(128), y=N-tiles(64))
  gemm_bf16<<<dim3(NROW / 128, 1152 / 64), 256, 0, stream>>>(
      hbuf, Wqkvt, nullptr, nullptr, qkv, NROW, 1152, 384, 0, 0);
  // 4. MFMA flash attention -> ob (bf16)
  attn_mfma<<<B_ * Hn, 256, 0, stream>>>(qkv, ob);
  // 5. x1 = x + ob@Wp + bp  -> d_out (fp32)
  gemm_bf16<<<dim3(NROW / 128, 384 / 64), 256, 0, stream>>>(
      ob, Wpt, bp, x, out, NROW, 384, 384, 0, 1);
  // 6. LN2: x1 -> h (bf16)
  ln_kernel<<<NROW, 128, 0, stream>>>(out, g2, be2, hbuf);
  // 7. FF1 + ReLU: [32768,384] @ [384,1536] -> bf16
  gemm_bf16<<<dim3(NROW / 128, 1536 / 64), 256, 0, stream>>>(
      hbuf, W1t, b1, nullptr, ff1, NROW, 1536, 384, 1, 0);
  // 8. out = x1 + ff1@W2 + b2 -> d_out (fp32)
  gemm_bf16<<<dim3(NROW / 128, 384 / 64), 256, 0, stream>>>(
      ff1, W2t, b2, out, out, NROW, 384, 1536, 0, 1);
}